// Round 1
// baseline (121.370 us; speedup 1.0000x reference)
//
#include <hip/hip_runtime.h>

// CondMul: out[n] = input[n] @ w[inds[n]] + b[inds[n]]
// N=262144 rows, 1024 experts, in=out=32, fp32.
//
// Strategy: counting-sort rows by expert (deterministic, no global atomics),
// then one block per expert with w staged in LDS once (kills the 1 GB L2
// w-refetch a naive gather kernel pays). HBM floor ~70 MB => ~11 us.

#define N_ROWS      262144
#define N_CLASSES   1024
#define IN_F        32
#define OUT_F       32
#define HIST_BLOCKS 64
#define ROWS_PER_HB (N_ROWS / HIST_BLOCKS)   // 4096, exact

// ---------------- K1: per-block histogram (LDS atomics) ----------------
__global__ __launch_bounds__(256) void k_hist(const int* __restrict__ inds,
                                              int* __restrict__ bc) {
    __shared__ int h[N_CLASSES];
    const int tid = threadIdx.x;
    for (int c = tid; c < N_CLASSES; c += 256) h[c] = 0;
    __syncthreads();
    const int base = blockIdx.x * ROWS_PER_HB;
    for (int k = 0; k < ROWS_PER_HB; k += 256) {
        int c = inds[base + k + tid];
        atomicAdd(&h[c], 1);
    }
    __syncthreads();
    for (int c = tid; c < N_CLASSES; c += 256)
        bc[blockIdx.x * N_CLASSES + c] = h[c];
}

// ------- K2: single block; per-class totals, scan, per-block starts -------
__global__ __launch_bounds__(1024) void k_scan(int* __restrict__ bc,
                                               int* __restrict__ cls_off) {
    __shared__ int s[N_CLASSES];
    const int c = threadIdx.x;  // 1024 threads == N_CLASSES
    int total = 0;
    for (int b = 0; b < HIST_BLOCKS; ++b) total += bc[b * N_CLASSES + c];
    s[c] = total;
    __syncthreads();
    // Hillis-Steele inclusive scan over classes
    for (int off = 1; off < N_CLASSES; off <<= 1) {
        int v = (c >= off) ? s[c - off] : 0;
        __syncthreads();
        s[c] += v;
        __syncthreads();
    }
    const int base = s[c] - total;  // exclusive prefix
    cls_off[c] = base;
    if (c == N_CLASSES - 1) cls_off[N_CLASSES] = s[c];  // == N_ROWS
    // turn bc[b][c] into the global start offset for (hist-block b, class c)
    int run = base;
    for (int b = 0; b < HIST_BLOCKS; ++b) {
        int t = bc[b * N_CLASSES + c];
        bc[b * N_CLASSES + c] = run;
        run += t;
    }
}

// ---------------- K3: scatter row ids into buckets (LDS cursors) ----------------
__global__ __launch_bounds__(256) void k_scatter(const int* __restrict__ inds,
                                                 const int* __restrict__ bc,
                                                 int* __restrict__ rowids) {
    __shared__ int cur[N_CLASSES];
    const int tid = threadIdx.x;
    for (int c = tid; c < N_CLASSES; c += 256)
        cur[c] = bc[blockIdx.x * N_CLASSES + c];
    __syncthreads();
    const int base = blockIdx.x * ROWS_PER_HB;
    for (int k = 0; k < ROWS_PER_HB; k += 256) {
        int row = base + k + tid;
        int c = inds[row];
        int pos = atomicAdd(&cur[c], 1);
        rowids[pos] = row;
    }
}

// ---------------- K4: one block per expert, w in LDS ----------------
// 256 threads = 4 waves. Lane -> (row-group rg = tid>>3, out-quad oq = tid&7).
// Each iteration the block does 32 rows; per lane: full input row in regs
// (8x float4, 8-way same-address broadcast loads), 32x ds_read_b128 of w
// (8 distinct addrs, broadcast -> conflict-free), 128 scalar FMAs.
__global__ __launch_bounds__(256) void k_condmul(const float* __restrict__ input,
                                                 const float* __restrict__ w,
                                                 const float* __restrict__ bias,
                                                 const int* __restrict__ rowids,
                                                 const int* __restrict__ cls_off,
                                                 float* __restrict__ out) {
    __shared__ float wlds[IN_F * OUT_F];  // 4 KiB
    const int cls = blockIdx.x;
    const int tid = threadIdx.x;

    // stage this expert's weights: 256 threads x 16 B = 4 KiB exactly
    ((float4*)wlds)[tid] = ((const float4*)(w + (size_t)cls * IN_F * OUT_F))[tid];

    const int oq = tid & 7;   // float4 column index (outputs oq*4 .. oq*4+3)
    const int rg = tid >> 3;  // 0..31 row slot within the block iteration
    const float4 bv = ((const float4*)(bias + (size_t)cls * OUT_F))[oq];
    const int start = cls_off[cls];
    const int count = cls_off[cls + 1] - start;
    __syncthreads();

    const float4* wl4 = (const float4*)wlds;
    const int iters = (count + 31) >> 5;
    for (int it = 0; it < iters; ++it) {
        const int ri = it * 32 + rg;
        const bool valid = ri < count;
        const int idx = valid ? ri : (count - 1);
        const int row = rowids[start + idx];

        const float4* xin = (const float4*)(input + (size_t)row * IN_F);
        float4 x[8];
#pragma unroll
        for (int j = 0; j < 8; ++j) x[j] = xin[j];

        float4 acc = bv;
#pragma unroll
        for (int j = 0; j < 8; ++j) {
            const float a0 = x[j].x, a1 = x[j].y, a2 = x[j].z, a3 = x[j].w;
            const float4 w0 = wl4[(j * 4 + 0) * (OUT_F / 4) + oq];
            const float4 w1 = wl4[(j * 4 + 1) * (OUT_F / 4) + oq];
            const float4 w2 = wl4[(j * 4 + 2) * (OUT_F / 4) + oq];
            const float4 w3 = wl4[(j * 4 + 3) * (OUT_F / 4) + oq];
            acc.x += a0 * w0.x; acc.y += a0 * w0.y; acc.z += a0 * w0.z; acc.w += a0 * w0.w;
            acc.x += a1 * w1.x; acc.y += a1 * w1.y; acc.z += a1 * w1.z; acc.w += a1 * w1.w;
            acc.x += a2 * w2.x; acc.y += a2 * w2.y; acc.z += a2 * w2.z; acc.w += a2 * w2.w;
            acc.x += a3 * w3.x; acc.y += a3 * w3.y; acc.z += a3 * w3.z; acc.w += a3 * w3.w;
        }
        if (valid)
            ((float4*)(out + (size_t)row * OUT_F))[oq] = acc;
    }
}

// ---------------- fallback: direct gather (used only if ws too small) ----------------
__global__ __launch_bounds__(256) void k_naive(const float* __restrict__ input,
                                               const int* __restrict__ inds,
                                               const float* __restrict__ w,
                                               const float* __restrict__ bias,
                                               float* __restrict__ out) {
    const int tid = threadIdx.x;
    const int oq = tid & 7;
    const int rg = tid >> 3;
    const int row = blockIdx.x * 32 + rg;
    if (row >= N_ROWS) return;
    const int c = inds[row];
    const float4* xin = (const float4*)(input + (size_t)row * IN_F);
    const float4* wr = (const float4*)(w + (size_t)c * IN_F * OUT_F);
    float4 acc = ((const float4*)(bias + (size_t)c * OUT_F))[oq];
#pragma unroll
    for (int j = 0; j < 8; ++j) {
        const float4 xv = xin[j];
        const float a0 = xv.x, a1 = xv.y, a2 = xv.z, a3 = xv.w;
        const float4 w0 = wr[(j * 4 + 0) * (OUT_F / 4) + oq];
        const float4 w1 = wr[(j * 4 + 1) * (OUT_F / 4) + oq];
        const float4 w2 = wr[(j * 4 + 2) * (OUT_F / 4) + oq];
        const float4 w3 = wr[(j * 4 + 3) * (OUT_F / 4) + oq];
        acc.x += a0 * w0.x; acc.y += a0 * w0.y; acc.z += a0 * w0.z; acc.w += a0 * w0.w;
        acc.x += a1 * w1.x; acc.y += a1 * w1.y; acc.z += a1 * w1.z; acc.w += a1 * w1.w;
        acc.x += a2 * w2.x; acc.y += a2 * w2.y; acc.z += a2 * w2.z; acc.w += a2 * w2.w;
        acc.x += a3 * w3.x; acc.y += a3 * w3.y; acc.z += a3 * w3.z; acc.w += a3 * w3.w;
    }
    ((float4*)(out + (size_t)row * OUT_F))[oq] = acc;
}

extern "C" void kernel_launch(void* const* d_in, const int* in_sizes, int n_in,
                              void* d_out, int out_size, void* d_ws, size_t ws_size,
                              hipStream_t stream) {
    const float* input = (const float*)d_in[0];  // [N, 32] fp32
    const int*   inds  = (const int*)d_in[1];    // [N] int32
    const float* w     = (const float*)d_in[2];  // [1024, 32, 32] fp32
    const float* bias  = (const float*)d_in[3];  // [1024, 1, 32] fp32
    float* out = (float*)d_out;                  // [N, 32] fp32

    // ws layout (ints): bc[64][1024] | cls_off[1025] (+3 pad) | rowids[N]
    int* ws = (int*)d_ws;
    int* bc      = ws;
    int* cls_off = ws + HIST_BLOCKS * N_CLASSES;
    int* rowids  = cls_off + N_CLASSES + 1 + 3;
    const size_t need = (size_t)(HIST_BLOCKS * N_CLASSES + N_CLASSES + 4 + N_ROWS) * sizeof(int);

    if (ws_size >= need) {
        k_hist<<<HIST_BLOCKS, 256, 0, stream>>>(inds, bc);
        k_scan<<<1, 1024, 0, stream>>>(bc, cls_off);
        k_scatter<<<HIST_BLOCKS, 256, 0, stream>>>(inds, bc, rowids);
        k_condmul<<<N_CLASSES, 256, 0, stream>>>(input, w, bias, rowids, cls_off, out);
    } else {
        k_naive<<<N_ROWS / 32, 256, 0, stream>>>(input, inds, w, bias, out);
    }
}